// Round 1
// baseline (2908.109 us; speedup 1.0000x reference)
//
#include <hip/hip_runtime.h>
#include <math.h>

#define N0v 200000
#define N1v 50000
#define N2v 10000
#define Dv  256
#define Cv  40
#define DEGv 10

#define BM 128
#define BN 128
#define BK 16

// ---------------- aggregation ----------------
// MODE 0: mean+max from same source (one gather)
// MODE 1: mean only
// MODE 2: max only
// MODE 3: mean from src_mean, max from src_max (different arrays)
template<int MODE>
__global__ __launch_bounds__(256) void agg_kernel(
    const float* __restrict__ src_mean, const float* __restrict__ src_max,
    const int* __restrict__ row,
    float* __restrict__ out_mean, float* __restrict__ out_max)
{
    const int t = blockIdx.x;
    const int d = threadIdx.x;
    const int ebase = t * DEGv;
    float s = 0.0f;
    float mx = -INFINITY;
#pragma unroll
    for (int k = 0; k < DEGv; ++k) {
        const int r = row[ebase + k];
        if (MODE == 0) {
            float v = src_mean[(size_t)r * Dv + d];
            s += v;
            mx = fmaxf(mx, v);
        } else if (MODE == 1) {
            s += src_mean[(size_t)r * Dv + d];
        } else if (MODE == 2) {
            mx = fmaxf(mx, src_max[(size_t)r * Dv + d]);
        } else {
            s += src_mean[(size_t)r * Dv + d];
            mx = fmaxf(mx, src_max[(size_t)r * Dv + d]);
        }
    }
    if (MODE != 2) out_mean[(size_t)t * Dv + d] = s * (1.0f / DEGv);
    if (MODE != 1) out_max[(size_t)t * Dv + d]  = mx;
}

// ---------------- fused dual GEMM:  H = [relu]( A1@W1 + A2@W2 + b ) ----------------
// A1: M x 256, A2: M x 256 (row-major), W1/W2: 256 x 256 (row-major), b: 256
// Output: Hout[m * ldc + col_off + n], n in [0,256)
template<bool RELU>
__global__ __launch_bounds__(256) void gemm_dual_kernel(
    const float* __restrict__ A1, const float* __restrict__ A2,
    const float* __restrict__ W1, const float* __restrict__ W2,
    const float* __restrict__ bias, float* __restrict__ Hout,
    int M, int ldc, int col_off)
{
    __shared__ float As1[BK][BM + 4];
    __shared__ float As2[BK][BM + 4];
    __shared__ float Ws1[BK][BN];
    __shared__ float Ws2[BK][BN];

    const int tid = threadIdx.x;
    const int m0 = blockIdx.x * BM;
    const int n0 = blockIdx.y * BN;
    const int tm = tid & 15;
    const int tn = tid >> 4;

    float acc[8][8] = {};

    for (int k0 = 0; k0 < Dv; k0 += BK) {
        // stage A tiles (transposed): BM*BK = 2048 elems, 8 per thread
#pragma unroll
        for (int i = 0; i < 8; ++i) {
            const int idx = tid + i * 256;
            const int k = idx & 15;
            const int m = idx >> 4;
            int gm = m0 + m;
            if (gm >= M) gm = M - 1;
            As1[k][m] = A1[(size_t)gm * Dv + k0 + k];
            As2[k][m] = A2[(size_t)gm * Dv + k0 + k];
        }
        // stage W tiles: BK*BN = 2048 elems
#pragma unroll
        for (int i = 0; i < 8; ++i) {
            const int idx = tid + i * 256;
            const int n = idx & 127;
            const int k = idx >> 7;
            Ws1[k][n] = W1[(size_t)(k0 + k) * Dv + n0 + n];
            Ws2[k][n] = W2[(size_t)(k0 + k) * Dv + n0 + n];
        }
        __syncthreads();

#pragma unroll
        for (int k = 0; k < BK; ++k) {
            float a1v[8], a2v[8], w1v[8], w2v[8];
            *(float4*)&a1v[0] = *(const float4*)&As1[k][tm * 8];
            *(float4*)&a1v[4] = *(const float4*)&As1[k][tm * 8 + 4];
            *(float4*)&a2v[0] = *(const float4*)&As2[k][tm * 8];
            *(float4*)&a2v[4] = *(const float4*)&As2[k][tm * 8 + 4];
            *(float4*)&w1v[0] = *(const float4*)&Ws1[k][tn * 8];
            *(float4*)&w1v[4] = *(const float4*)&Ws1[k][tn * 8 + 4];
            *(float4*)&w2v[0] = *(const float4*)&Ws2[k][tn * 8];
            *(float4*)&w2v[4] = *(const float4*)&Ws2[k][tn * 8 + 4];
#pragma unroll
            for (int i = 0; i < 8; ++i)
#pragma unroll
                for (int j = 0; j < 8; ++j)
                    acc[i][j] += a1v[i] * w1v[j] + a2v[i] * w2v[j];
        }
        __syncthreads();
    }

    const int mbase = m0 + tm * 8;
    const int nbase = n0 + tn * 8;
    float bv[8];
#pragma unroll
    for (int j = 0; j < 8; ++j) bv[j] = bias[nbase + j];

#pragma unroll
    for (int i = 0; i < 8; ++i) {
        const int gm = mbase + i;
        if (gm < M) {
            float v[8];
#pragma unroll
            for (int j = 0; j < 8; ++j) {
                v[j] = acc[i][j] + bv[j];
                if (RELU) v[j] = fmaxf(v[j], 0.0f);
            }
            float* dst = &Hout[(size_t)gm * ldc + col_off + nbase];
            *(float4*)&dst[0] = *(float4*)&v[0];
            *(float4*)&dst[4] = *(float4*)&v[4];
        }
    }
}

// ---------------- post: logits = ocat @ W_post + b_post; log_softmax ----------------
__global__ __launch_bounds__(64) void post_kernel(
    const float* __restrict__ ocat, const float* __restrict__ Wp,
    const float* __restrict__ bp, float* __restrict__ out)
{
    __shared__ float srow[2 * Dv];
    __shared__ float slog[Cv];
    __shared__ float s_lse;

    const int t = blockIdx.x;
    const int tid = threadIdx.x;

    for (int i = tid; i < 2 * Dv; i += 64)
        srow[i] = ocat[(size_t)t * (2 * Dv) + i];
    __syncthreads();

    if (tid < Cv) {
        float acc = bp[tid];
#pragma unroll 8
        for (int k = 0; k < 2 * Dv; ++k)
            acc += srow[k] * Wp[(size_t)k * Cv + tid];
        slog[tid] = acc;
    }
    __syncthreads();

    if (tid == 0) {
        float m = slog[0];
        for (int c = 1; c < Cv; ++c) m = fmaxf(m, slog[c]);
        float s = 0.0f;
        for (int c = 0; c < Cv; ++c) s += expf(slog[c] - m);
        s_lse = m + logf(s);
    }
    __syncthreads();

    if (tid < Cv)
        out[(size_t)t * Cv + tid] = slog[tid] - s_lse;
}

extern "C" void kernel_launch(void* const* d_in, const int* in_sizes, int n_in,
                              void* d_out, int out_size, void* d_ws, size_t ws_size,
                              hipStream_t stream)
{
    const float* x      = (const float*)d_in[0];
    const int*   ei0    = (const int*)d_in[1];
    const int*   ei1    = (const int*)d_in[2];
    const float* Wl_m0  = (const float*)d_in[3];
    const float* Wr_m0  = (const float*)d_in[4];
    const float* b_m0   = (const float*)d_in[5];
    const float* Wl_x0  = (const float*)d_in[6];
    const float* Wr_x0  = (const float*)d_in[7];
    const float* b_x0   = (const float*)d_in[8];
    const float* Wl_m1  = (const float*)d_in[9];
    const float* Wr_m1  = (const float*)d_in[10];
    const float* b_m1   = (const float*)d_in[11];
    const float* Wl_x1  = (const float*)d_in[12];
    const float* Wr_x1  = (const float*)d_in[13];
    const float* b_x1   = (const float*)d_in[14];
    const float* W_post = (const float*)d_in[15];
    const float* b_post = (const float*)d_in[16];
    float* out = (float*)d_out;

    const int* row0 = ei0;                // edge_index0[0]
    const int* row1 = ei1;                // edge_index1[0]

    char* ws = (char*)d_ws;
    const size_t nd = (size_t)N1v * Dv * sizeof(float);   // 51.2 MB
    float* bufA = (float*)(ws);
    float* bufB = (float*)(ws + nd);
    float* bufC = (float*)(ws + 2 * nd);
    float* bufD = (float*)(ws + 3 * nd);

    const dim3 blk(256);
    const dim3 g0((N1v + BM - 1) / BM, Dv / BN);   // 391 x 2
    const dim3 g1((N2v + BM - 1) / BM, Dv / BN);   // 79 x 2

    if (ws_size >= 4 * nd) {
        // 4-buffer plan: one gather pass for layer-0 agg
        agg_kernel<0><<<N1v, blk, 0, stream>>>(x, x, row0, bufA, bufB);
        gemm_dual_kernel<true><<<g0, blk, 0, stream>>>(bufA, x, Wl_m0, Wr_m0, b_m0, bufC, N1v, Dv, 0);   // h_m
        gemm_dual_kernel<true><<<g0, blk, 0, stream>>>(bufB, x, Wl_x0, Wr_x0, b_x0, bufD, N1v, Dv, 0);   // h_x
        agg_kernel<3><<<N2v, blk, 0, stream>>>(bufC, bufD, row1, bufA, bufA + (size_t)N2v * Dv);
        gemm_dual_kernel<false><<<g1, blk, 0, stream>>>(bufA, x, Wl_m1, Wr_m1, b_m1, bufB, N2v, 2 * Dv, 0);
        gemm_dual_kernel<false><<<g1, blk, 0, stream>>>(bufA + (size_t)N2v * Dv, x, Wl_x1, Wr_x1, b_x1, bufB, N2v, 2 * Dv, Dv);
        post_kernel<<<N2v, dim3(64), 0, stream>>>(bufB, W_post, b_post, out);
    } else {
        // 3-buffer plan: re-gather x for the max aggregation
        agg_kernel<1><<<N1v, blk, 0, stream>>>(x, x, row0, bufA, nullptr);
        gemm_dual_kernel<true><<<g0, blk, 0, stream>>>(bufA, x, Wl_m0, Wr_m0, b_m0, bufB, N1v, Dv, 0);   // h_m
        agg_kernel<2><<<N1v, blk, 0, stream>>>(x, x, row0, nullptr, bufA);
        gemm_dual_kernel<true><<<g0, blk, 0, stream>>>(bufA, x, Wl_x0, Wr_x0, b_x0, bufC, N1v, Dv, 0);   // h_x
        agg_kernel<3><<<N2v, blk, 0, stream>>>(bufB, bufC, row1, bufA, bufA + (size_t)N2v * Dv);
        float* ocat = bufA + (size_t)2 * N2v * Dv;
        gemm_dual_kernel<false><<<g1, blk, 0, stream>>>(bufA, x, Wl_m1, Wr_m1, b_m1, ocat, N2v, 2 * Dv, 0);
        gemm_dual_kernel<false><<<g1, blk, 0, stream>>>(bufA + (size_t)N2v * Dv, x, Wl_x1, Wr_x1, b_x1, ocat, N2v, 2 * Dv, Dv);
        post_kernel<<<N2v, dim3(64), 0, stream>>>(ocat, W_post, b_post, out);
    }
}

// Round 2
// 290.109 us; speedup vs baseline: 10.0242x; 10.0242x over previous
//
#include <hip/hip_runtime.h>
#include <hip/hip_bf16.h>
#include <math.h>

#define N0v 200000
#define N1v 50000
#define N2v 10000
#define Dv  256
#define Cv  40
#define DEGv 10

typedef __attribute__((ext_vector_type(8))) short          s16x8;
typedef __attribute__((ext_vector_type(8))) unsigned short u16x8;
typedef __attribute__((ext_vector_type(4))) float          f32x4;

static __device__ __forceinline__ unsigned short f2bf(float f) {
    __hip_bfloat16 h = __float2bfloat16(f);
    return *reinterpret_cast<unsigned short*>(&h);
}
static __device__ __forceinline__ float bf2f(unsigned short u) {
    __hip_bfloat16 h = *reinterpret_cast<__hip_bfloat16*>(&u);
    return __bfloat162float(h);
}

// ---- convert one weight pair (Wl,Wr each 256x256 f32) into WT[n][k] bf16, k<256->Wl, k>=256->Wr
__global__ __launch_bounds__(256) void conv_wt_kernel(
    const float* __restrict__ Wl, const float* __restrict__ Wr, unsigned short* __restrict__ WT)
{
    const int n = blockIdx.x;      // 256 blocks
    const int k = threadIdx.x;     // 256 threads
    WT[(size_t)n * 512 + k]       = f2bf(Wl[(size_t)k * Dv + n]);
    WT[(size_t)n * 512 + 256 + k] = f2bf(Wr[(size_t)k * Dv + n]);
}

// ---- f32 -> bf16 bulk convert (4 elems/thread)
__global__ __launch_bounds__(256) void conv_rows_kernel(
    const float* __restrict__ src, unsigned short* __restrict__ dst, int n_elems)
{
    const int i = (blockIdx.x * 256 + threadIdx.x) * 4;
    if (i + 3 < n_elems) {
        float4 v = *(const float4*)(src + i);
        unsigned short o[4] = { f2bf(v.x), f2bf(v.y), f2bf(v.z), f2bf(v.w) };
        *(uint2*)(dst + i) = *(uint2*)o;
    }
}

// ---- layer-0 aggregation: gather f32 x, write mean & max as bf16
__global__ __launch_bounds__(256) void agg0_kernel(
    const float* __restrict__ x, const int* __restrict__ row,
    unsigned short* __restrict__ om, unsigned short* __restrict__ ox)
{
    const int t = blockIdx.x;
    const int d = threadIdx.x;
    const int eb = t * DEGv;
    float s = 0.0f, mx = -INFINITY;
#pragma unroll
    for (int k = 0; k < DEGv; ++k) {
        const int r = row[eb + k];
        float v = x[(size_t)r * Dv + d];
        s += v;
        mx = fmaxf(mx, v);
    }
    om[(size_t)t * Dv + d] = f2bf(s * (1.0f / DEGv));
    ox[(size_t)t * Dv + d] = f2bf(mx);
}

// ---- layer-1 aggregation: gather bf16 h_m / h_x, write mean & max bf16
__global__ __launch_bounds__(256) void agg1_kernel(
    const unsigned short* __restrict__ hm, const unsigned short* __restrict__ hx,
    const int* __restrict__ row,
    unsigned short* __restrict__ om, unsigned short* __restrict__ ox)
{
    const int t = blockIdx.x;
    const int d = threadIdx.x;
    const int eb = t * DEGv;
    float s = 0.0f, mx = -INFINITY;
#pragma unroll
    for (int k = 0; k < DEGv; ++k) {
        const int r = row[eb + k];
        s  += bf2f(hm[(size_t)r * Dv + d]);
        mx = fmaxf(mx, bf2f(hx[(size_t)r * Dv + d]));
    }
    om[(size_t)t * Dv + d] = f2bf(s * (1.0f / DEGv));
    ox[(size_t)t * Dv + d] = f2bf(mx);
}

// ---- bf16 MFMA GEMM: out = [relu]( [A1|A2] (Mx512) @ WT^T (512x256) + bias )
// A1,A2: [M][256] bf16 row-major. WT: [256][512] bf16 ("B^T": WT[n][k]).
// 128x128 tile, 4 waves, each wave 64x64 = 4x4 fragments of 16x16x32.
template<int RELU, int OUTBF>
__global__ __launch_bounds__(256) void gemm_bf16_kernel(
    const unsigned short* __restrict__ A1, const unsigned short* __restrict__ A2,
    const unsigned short* __restrict__ WT, const float* __restrict__ bias,
    void* __restrict__ outp, int M, int ldc, int col_off)
{
    __shared__ unsigned short Asb[128 * 40];   // padded rows: 40 elems (80 B) kill bank conflicts
    __shared__ unsigned short Bsb[128 * 40];

    const int tid  = threadIdx.x;
    const int lane = tid & 63;
    const int w    = tid >> 6;
    const int wr   = w >> 1;
    const int wc   = w & 1;
    const int m0   = blockIdx.x * 128;
    const int n0   = blockIdx.y * 128;

    f32x4 acc[4][4] = {};

    // staging assignment: thread t covers row sr, 16-elem half sh
    const int sr = tid >> 1;
    const int sh = (tid & 1) * 16;
    int agm = m0 + sr; if (agm >= M) agm = M - 1;
    const unsigned short* a1p = A1 + (size_t)agm * Dv;
    const unsigned short* a2p = A2 + (size_t)agm * Dv;
    const unsigned short* wp  = WT + (size_t)(n0 + sr) * 512;

    const int kq = (lane >> 4) * 8;   // k-offset of this lane's fragment slice
    const int fr = lane & 15;         // fragment row/col index

    for (int k0 = 0; k0 < 512; k0 += 32) {
        const unsigned short* ap = (k0 < 256) ? (a1p + k0) : (a2p + (k0 - 256));
        u16x8 av0 = *(const u16x8*)(ap + sh);
        u16x8 av1 = *(const u16x8*)(ap + sh + 8);
        u16x8 bv0 = *(const u16x8*)(wp + k0 + sh);
        u16x8 bv1 = *(const u16x8*)(wp + k0 + sh + 8);

        __syncthreads();   // previous iteration's reads done before overwrite
        *(u16x8*)&Asb[sr * 40 + sh]     = av0;
        *(u16x8*)&Asb[sr * 40 + sh + 8] = av1;
        *(u16x8*)&Bsb[sr * 40 + sh]     = bv0;
        *(u16x8*)&Bsb[sr * 40 + sh + 8] = bv1;
        __syncthreads();

        s16x8 af[4], bfr[4];
#pragma unroll
        for (int i = 0; i < 4; ++i) {
            af[i]  = *(const s16x8*)&Asb[(wr * 64 + i * 16 + fr) * 40 + kq];
            bfr[i] = *(const s16x8*)&Bsb[(wc * 64 + i * 16 + fr) * 40 + kq];
        }
#pragma unroll
        for (int i = 0; i < 4; ++i)
#pragma unroll
            for (int j = 0; j < 4; ++j)
                acc[i][j] = __builtin_amdgcn_mfma_f32_16x16x32_bf16(af[i], bfr[j], acc[i][j], 0, 0, 0);
    }

    // epilogue: D[row=(lane>>4)*4+reg][col=lane&15] per 16x16 fragment
#pragma unroll
    for (int i = 0; i < 4; ++i) {
#pragma unroll
        for (int reg = 0; reg < 4; ++reg) {
            const int gr = m0 + wr * 64 + i * 16 + (lane >> 4) * 4 + reg;
            if (gr < M) {
#pragma unroll
                for (int j = 0; j < 4; ++j) {
                    const int gc = n0 + wc * 64 + j * 16 + fr;
                    float v = acc[i][j][reg] + bias[gc];
                    if (RELU) v = fmaxf(v, 0.0f);
                    if (OUTBF)
                        ((unsigned short*)outp)[(size_t)gr * ldc + col_off + gc] = f2bf(v);
                    else
                        ((float*)outp)[(size_t)gr * ldc + col_off + gc] = v;
                }
            }
        }
    }
}

// ---- post: logits = ocat @ W_post + b_post; log_softmax
__global__ __launch_bounds__(64) void post_kernel(
    const float* __restrict__ ocat, const float* __restrict__ Wp,
    const float* __restrict__ bp, float* __restrict__ out)
{
    __shared__ float srow[2 * Dv];
    __shared__ float slog[Cv];
    __shared__ float s_lse;

    const int t = blockIdx.x;
    const int tid = threadIdx.x;

    for (int i = tid; i < 2 * Dv; i += 64)
        srow[i] = ocat[(size_t)t * (2 * Dv) + i];
    __syncthreads();

    if (tid < Cv) {
        float acc = bp[tid];
#pragma unroll 8
        for (int k = 0; k < 2 * Dv; ++k)
            acc += srow[k] * Wp[(size_t)k * Cv + tid];
        slog[tid] = acc;
    }
    __syncthreads();

    if (tid == 0) {
        float m = slog[0];
        for (int c = 1; c < Cv; ++c) m = fmaxf(m, slog[c]);
        float s = 0.0f;
        for (int c = 0; c < Cv; ++c) s += expf(slog[c] - m);
        s_lse = m + logf(s);
    }
    __syncthreads();

    if (tid < Cv)
        out[(size_t)t * Cv + tid] = slog[tid] - s_lse;
}

extern "C" void kernel_launch(void* const* d_in, const int* in_sizes, int n_in,
                              void* d_out, int out_size, void* d_ws, size_t ws_size,
                              hipStream_t stream)
{
    const float* x      = (const float*)d_in[0];
    const int*   ei0    = (const int*)d_in[1];
    const int*   ei1    = (const int*)d_in[2];
    const float* Wl_m0  = (const float*)d_in[3];
    const float* Wr_m0  = (const float*)d_in[4];
    const float* b_m0   = (const float*)d_in[5];
    const float* Wl_x0  = (const float*)d_in[6];
    const float* Wr_x0  = (const float*)d_in[7];
    const float* b_x0   = (const float*)d_in[8];
    const float* Wl_m1  = (const float*)d_in[9];
    const float* Wr_m1  = (const float*)d_in[10];
    const float* b_m1   = (const float*)d_in[11];
    const float* Wl_x1  = (const float*)d_in[12];
    const float* Wr_x1  = (const float*)d_in[13];
    const float* b_x1   = (const float*)d_in[14];
    const float* W_post = (const float*)d_in[15];
    const float* b_post = (const float*)d_in[16];
    float* out = (float*)d_out;

    const int* row0 = ei0;   // edge_index0[0]
    const int* row1 = ei1;   // edge_index1[0]

    // workspace layout (bytes); NB = 50000*256*2
    char* ws = (char*)d_ws;
    const size_t NB = (size_t)N1v * Dv * 2;            // 25,600,000
    unsigned short* xtb  = (unsigned short*)(ws);                 // x[:50000] bf16
    unsigned short* bufB1 = (unsigned short*)(ws + NB);           // am -> hx
    unsigned short* bufB2 = (unsigned short*)(ws + 2 * NB);       // ax -> a1m,a1x
    char*           bufB3 = ws + 3 * NB;                          // hm -> ocat(f32)
    unsigned short* WT0m = (unsigned short*)(ws + 4 * NB);
    unsigned short* WT0x = WT0m + (size_t)256 * 512;
    unsigned short* WT1m = WT0x + (size_t)256 * 512;
    unsigned short* WT1x = WT1m + (size_t)256 * 512;

    unsigned short* am  = bufB1;
    unsigned short* ax  = bufB2;
    unsigned short* hm  = (unsigned short*)bufB3;
    unsigned short* hx  = bufB1;                    // reuse after am dead
    unsigned short* a1m = bufB2;                    // reuse after ax dead
    unsigned short* a1x = bufB2 + (size_t)N2v * Dv;
    float*          ocat = (float*)bufB3;           // reuse after hm dead

    const dim3 blk(256);

    // weight transpose+convert (tiny)
    conv_wt_kernel<<<256, blk, 0, stream>>>(Wl_m0, Wr_m0, WT0m);
    conv_wt_kernel<<<256, blk, 0, stream>>>(Wl_x0, Wr_x0, WT0x);
    conv_wt_kernel<<<256, blk, 0, stream>>>(Wl_m1, Wr_m1, WT1m);
    conv_wt_kernel<<<256, blk, 0, stream>>>(Wl_x1, Wr_x1, WT1x);
    // x[:50000] -> bf16
    conv_rows_kernel<<<(N1v * Dv / 4 + 255) / 256, blk, 0, stream>>>(x, xtb, N1v * Dv);

    // layer 0
    agg0_kernel<<<N1v, blk, 0, stream>>>(x, row0, am, ax);
    const dim3 g0((N1v + 127) / 128, 2);
    gemm_bf16_kernel<1, 1><<<g0, blk, 0, stream>>>(am, xtb, WT0m, b_m0, hm, N1v, Dv, 0);
    gemm_bf16_kernel<1, 1><<<g0, blk, 0, stream>>>(ax, xtb, WT0x, b_x0, hx, N1v, Dv, 0);

    // layer 1
    agg1_kernel<<<N2v, blk, 0, stream>>>(hm, hx, row1, a1m, a1x);
    const dim3 g1((N2v + 127) / 128, 2);
    gemm_bf16_kernel<0, 0><<<g1, blk, 0, stream>>>(a1m, xtb, WT1m, b_m1, ocat, N2v, 2 * Dv, 0);
    gemm_bf16_kernel<0, 0><<<g1, blk, 0, stream>>>(a1x, xtb, WT1x, b_x1, ocat, N2v, 2 * Dv, Dv);

    // post
    post_kernel<<<N2v, dim3(64), 0, stream>>>(ocat, W_post, b_post, out);
}

// Round 3
// 249.910 us; speedup vs baseline: 11.6366x; 1.1609x over previous
//
#include <hip/hip_runtime.h>
#include <hip/hip_bf16.h>
#include <math.h>

#define N0v 200000
#define N1v 50000
#define N2v 10000
#define Dv  256
#define Cv  40
#define DEGv 10

typedef __attribute__((ext_vector_type(8))) short          s16x8;
typedef __attribute__((ext_vector_type(8))) unsigned short u16x8;
typedef __attribute__((ext_vector_type(4))) float          f32x4;

static __device__ __forceinline__ unsigned short f2bf(float f) {
    __hip_bfloat16 h = __float2bfloat16(f);
    return *reinterpret_cast<unsigned short*>(&h);
}
static __device__ __forceinline__ float bf2f(unsigned short u) {
    __hip_bfloat16 h = *reinterpret_cast<__hip_bfloat16*>(&u);
    return __bfloat162float(h);
}

// async global -> LDS, 16B per lane, wave-uniform LDS base + lane*16 dest
static __device__ __forceinline__ void gload16(const void* g, void* l) {
    __builtin_amdgcn_global_load_lds(
        (const __attribute__((address_space(1))) unsigned int*)g,
        (__attribute__((address_space(3))) unsigned int*)l, 16, 0, 0);
}

// ---- all 4 weight pairs -> WT[n][k] bf16 (k<256 = Wl col, k>=256 = Wr col)
__global__ __launch_bounds__(256) void conv_wt_all_kernel(
    const float* __restrict__ Wl0, const float* __restrict__ Wr0,
    const float* __restrict__ Wl1, const float* __restrict__ Wr1,
    const float* __restrict__ Wl2, const float* __restrict__ Wr2,
    const float* __restrict__ Wl3, const float* __restrict__ Wr3,
    unsigned short* __restrict__ WT0, unsigned short* __restrict__ WT1,
    unsigned short* __restrict__ WT2, unsigned short* __restrict__ WT3)
{
    const int p = blockIdx.y;
    const float* Wl = (p == 0) ? Wl0 : (p == 1) ? Wl1 : (p == 2) ? Wl2 : Wl3;
    const float* Wr = (p == 0) ? Wr0 : (p == 1) ? Wr1 : (p == 2) ? Wr2 : Wr3;
    unsigned short* WT = (p == 0) ? WT0 : (p == 1) ? WT1 : (p == 2) ? WT2 : WT3;
    const int n = blockIdx.x;
    const int k = threadIdx.x;
    WT[(size_t)n * 512 + k]       = f2bf(Wl[(size_t)k * Dv + n]);
    WT[(size_t)n * 512 + 256 + k] = f2bf(Wr[(size_t)k * Dv + n]);
}

// ---- f32 -> bf16, 8 elems/thread
__global__ __launch_bounds__(256) void conv_rows_kernel(
    const float* __restrict__ src, unsigned short* __restrict__ dst, int n_elems)
{
    const int i = (blockIdx.x * 256 + threadIdx.x) * 8;
    if (i + 7 < n_elems) {
        float4 v0 = *(const float4*)(src + i);
        float4 v1 = *(const float4*)(src + i + 4);
        unsigned short o[8] = { f2bf(v0.x), f2bf(v0.y), f2bf(v0.z), f2bf(v0.w),
                                f2bf(v1.x), f2bf(v1.y), f2bf(v1.z), f2bf(v1.w) };
        *(u16x8*)(dst + i) = *(u16x8*)o;
    }
}

// ---- layer-0 aggregation: gather f32 x (float4/lane), write mean & max bf16
__global__ __launch_bounds__(256) void agg0_kernel(
    const float* __restrict__ x, const int* __restrict__ row,
    unsigned short* __restrict__ om, unsigned short* __restrict__ ox)
{
    const int t = blockIdx.x * 4 + (threadIdx.x >> 6);
    const int c = threadIdx.x & 63;              // float4 lane
    const int eb = t * DEGv;
    float4 s = make_float4(0.f, 0.f, 0.f, 0.f);
    float4 mx = make_float4(-INFINITY, -INFINITY, -INFINITY, -INFINITY);
#pragma unroll
    for (int k = 0; k < DEGv; ++k) {
        const int r = row[eb + k];
        float4 v = ((const float4*)x)[(size_t)r * 64 + c];
        s.x += v.x; s.y += v.y; s.z += v.z; s.w += v.w;
        mx.x = fmaxf(mx.x, v.x); mx.y = fmaxf(mx.y, v.y);
        mx.z = fmaxf(mx.z, v.z); mx.w = fmaxf(mx.w, v.w);
    }
    const float inv = 1.0f / DEGv;
    unsigned short osum[4] = { f2bf(s.x * inv), f2bf(s.y * inv), f2bf(s.z * inv), f2bf(s.w * inv) };
    unsigned short omax[4] = { f2bf(mx.x), f2bf(mx.y), f2bf(mx.z), f2bf(mx.w) };
    *(uint2*)&om[(size_t)t * Dv + c * 4] = *(uint2*)osum;
    *(uint2*)&ox[(size_t)t * Dv + c * 4] = *(uint2*)omax;
}

// ---- layer-1 aggregation: gather bf16 (u16x8/lane), write mean & max bf16
__global__ __launch_bounds__(256) void agg1_kernel(
    const unsigned short* __restrict__ hm, const unsigned short* __restrict__ hx,
    const int* __restrict__ row,
    unsigned short* __restrict__ om, unsigned short* __restrict__ ox)
{
    const int t = blockIdx.x * 8 + (threadIdx.x >> 5);
    const int c = threadIdx.x & 31;              // u16x8 lane
    const int eb = t * DEGv;
    float s[8] = {};
    float mx[8] = { -INFINITY, -INFINITY, -INFINITY, -INFINITY,
                    -INFINITY, -INFINITY, -INFINITY, -INFINITY };
#pragma unroll
    for (int k = 0; k < DEGv; ++k) {
        const int r = row[eb + k];
        u16x8 vm = ((const u16x8*)hm)[(size_t)r * 32 + c];
        u16x8 vx = ((const u16x8*)hx)[(size_t)r * 32 + c];
#pragma unroll
        for (int j = 0; j < 8; ++j) {
            s[j]  += bf2f(vm[j]);
            mx[j]  = fmaxf(mx[j], bf2f(vx[j]));
        }
    }
    const float inv = 1.0f / DEGv;
    unsigned short osum[8], omax[8];
#pragma unroll
    for (int j = 0; j < 8; ++j) { osum[j] = f2bf(s[j] * inv); omax[j] = f2bf(mx[j]); }
    *(u16x8*)&om[(size_t)t * Dv + c * 8] = *(u16x8*)osum;
    *(u16x8*)&ox[(size_t)t * Dv + c * 8] = *(u16x8*)omax;
}

// ---- bf16 MFMA GEMM (m97 structure): out_z = [relu]( [A1_z|A2] @ WT_z^T + bias_z )
// A1_z, A2: [M][256] bf16 row-major; WT_z: [256][512] bf16 (B^T layout).
// 128x128 tile, BK=32, 4 waves, global_load_lds staging, linear LDS.
template<int RELU, int OUTBF>
__global__ __launch_bounds__(256) void gemm_mfma_kernel(
    const unsigned short* __restrict__ A1a, const unsigned short* __restrict__ A1b,
    const unsigned short* __restrict__ A2,
    const unsigned short* __restrict__ WTa, const unsigned short* __restrict__ WTb,
    const float* __restrict__ biasa, const float* __restrict__ biasb,
    void* outa, void* outb, int M, int ldc, int col_step)
{
    __shared__ unsigned short Asb[128 * 32];
    __shared__ unsigned short Bsb[128 * 32];

    const int z = blockIdx.z;
    const unsigned short* A1 = z ? A1b : A1a;
    const unsigned short* WT = z ? WTb : WTa;
    const float* bias = z ? biasb : biasa;
    void* outp = z ? outb : outa;
    const int col_off = z * col_step;

    const int tid  = threadIdx.x;
    const int lane = tid & 63;
    const int w    = tid >> 6;
    const int wr   = w >> 1, wc = w & 1;
    const int m0   = blockIdx.x * 128, n0 = blockIdx.y * 128;

    // staging: wave w covers tile rows w*32 .. w*32+31, two 16-row instructions
    const int srow = w * 32 + (lane >> 2);
    const int ca   = (lane & 3) * 8;
    int gmA0 = m0 + srow;      if (gmA0 >= M) gmA0 = M - 1;
    int gmA1 = m0 + srow + 16; if (gmA1 >= M) gmA1 = M - 1;
    const unsigned short* pA1_0 = A1 + (size_t)gmA0 * Dv + ca;
    const unsigned short* pA1_1 = A1 + (size_t)gmA1 * Dv + ca;
    const unsigned short* pA2_0 = A2 + (size_t)gmA0 * Dv + ca;
    const unsigned short* pA2_1 = A2 + (size_t)gmA1 * Dv + ca;
    const unsigned short* pB_0  = WT + (size_t)(n0 + srow) * 512 + ca;
    const unsigned short* pB_1  = WT + (size_t)(n0 + srow + 16) * 512 + ca;

    unsigned short* lA0 = &Asb[w * 1024];
    unsigned short* lA1 = &Asb[w * 1024 + 512];
    unsigned short* lB0 = &Bsb[w * 1024];
    unsigned short* lB1 = &Bsb[w * 1024 + 512];

    const int kq = (lane >> 4) * 8;
    const int fr = lane & 15;

    f32x4 acc[4][4] = {};

    for (int k0 = 0; k0 < 512; k0 += 32) {
        const unsigned short* a0 = (k0 < 256) ? pA1_0 + k0 : pA2_0 + (k0 - 256);
        const unsigned short* a1 = (k0 < 256) ? pA1_1 + k0 : pA2_1 + (k0 - 256);
        __syncthreads();                 // prior ds_reads done before overwrite
        gload16(a0, lA0);
        gload16(a1, lA1);
        gload16(pB_0 + k0, lB0);
        gload16(pB_1 + k0, lB1);
        __syncthreads();                 // compiler drains vmcnt(0) before barrier

        s16x8 af[4], bfr[4];
#pragma unroll
        for (int i = 0; i < 4; ++i) {
            af[i]  = *(const s16x8*)&Asb[(wr * 64 + i * 16 + fr) * 32 + kq];
            bfr[i] = *(const s16x8*)&Bsb[(wc * 64 + i * 16 + fr) * 32 + kq];
        }
#pragma unroll
        for (int i = 0; i < 4; ++i)
#pragma unroll
            for (int j = 0; j < 4; ++j)
                acc[i][j] = __builtin_amdgcn_mfma_f32_16x16x32_bf16(af[i], bfr[j], acc[i][j], 0, 0, 0);
    }

    // epilogue: C/D map col=lane&15, row=(lane>>4)*4+reg
#pragma unroll
    for (int i = 0; i < 4; ++i) {
#pragma unroll
        for (int reg = 0; reg < 4; ++reg) {
            const int gr = m0 + wr * 64 + i * 16 + (lane >> 4) * 4 + reg;
            if (gr < M) {
#pragma unroll
                for (int j = 0; j < 4; ++j) {
                    const int gc = n0 + wc * 64 + j * 16 + fr;
                    float v = acc[i][j][reg] + bias[gc];
                    if (RELU) v = fmaxf(v, 0.0f);
                    if (OUTBF)
                        ((unsigned short*)outp)[(size_t)gr * ldc + col_off + gc] = f2bf(v);
                    else
                        ((float*)outp)[(size_t)gr * ldc + col_off + gc] = v;
                }
            }
        }
    }
}

// ---- post: logits = ocat @ W_post + b_post; log_softmax
__global__ __launch_bounds__(64) void post_kernel(
    const float* __restrict__ ocat, const float* __restrict__ Wp,
    const float* __restrict__ bp, float* __restrict__ out)
{
    __shared__ float srow[2 * Dv];
    __shared__ float slog[Cv];
    __shared__ float s_lse;

    const int t = blockIdx.x;
    const int tid = threadIdx.x;

    for (int i = tid; i < 2 * Dv; i += 64)
        srow[i] = ocat[(size_t)t * (2 * Dv) + i];
    __syncthreads();

    if (tid < Cv) {
        float acc = bp[tid];
#pragma unroll 8
        for (int k = 0; k < 2 * Dv; ++k)
            acc += srow[k] * Wp[(size_t)k * Cv + tid];
        slog[tid] = acc;
    }
    __syncthreads();

    if (tid == 0) {
        float m = slog[0];
        for (int c = 1; c < Cv; ++c) m = fmaxf(m, slog[c]);
        float s = 0.0f;
        for (int c = 0; c < Cv; ++c) s += expf(slog[c] - m);
        s_lse = m + logf(s);
    }
    __syncthreads();

    if (tid < Cv)
        out[(size_t)t * Cv + tid] = slog[tid] - s_lse;
}

extern "C" void kernel_launch(void* const* d_in, const int* in_sizes, int n_in,
                              void* d_out, int out_size, void* d_ws, size_t ws_size,
                              hipStream_t stream)
{
    const float* x      = (const float*)d_in[0];
    const int*   ei0    = (const int*)d_in[1];
    const int*   ei1    = (const int*)d_in[2];
    const float* Wl_m0  = (const float*)d_in[3];
    const float* Wr_m0  = (const float*)d_in[4];
    const float* b_m0   = (const float*)d_in[5];
    const float* Wl_x0  = (const float*)d_in[6];
    const float* Wr_x0  = (const float*)d_in[7];
    const float* b_x0   = (const float*)d_in[8];
    const float* Wl_m1  = (const float*)d_in[9];
    const float* Wr_m1  = (const float*)d_in[10];
    const float* b_m1   = (const float*)d_in[11];
    const float* Wl_x1  = (const float*)d_in[12];
    const float* Wr_x1  = (const float*)d_in[13];
    const float* b_x1   = (const float*)d_in[14];
    const float* W_post = (const float*)d_in[15];
    const float* b_post = (const float*)d_in[16];
    float* out = (float*)d_out;

    const int* row0 = ei0;   // edge_index0[0]
    const int* row1 = ei1;   // edge_index1[0]

    // workspace layout
    char* ws = (char*)d_ws;
    const size_t NB = (size_t)N1v * Dv * 2;                        // 25.6 MB
    unsigned short* xtb = (unsigned short*)(ws);                   // x[:50000] bf16
    unsigned short* am  = (unsigned short*)(ws + NB);
    unsigned short* ax  = (unsigned short*)(ws + 2 * NB);
    unsigned short* hm  = (unsigned short*)(ws + 3 * NB);
    unsigned short* hx  = (unsigned short*)(ws + 4 * NB);
    unsigned short* a1m = (unsigned short*)(ws + 5 * NB);
    unsigned short* a1x = a1m + (size_t)N2v * Dv;
    float*          ocat = (float*)(ws + 5 * NB + (size_t)2 * N2v * Dv * 2);
    unsigned short* WT0m = (unsigned short*)((char*)ocat + (size_t)N2v * 2 * Dv * 4);
    unsigned short* WT0x = WT0m + (size_t)256 * 512;
    unsigned short* WT1m = WT0x + (size_t)256 * 512;
    unsigned short* WT1x = WT1m + (size_t)256 * 512;

    const dim3 blk(256);

    // prep (independent of each other)
    conv_wt_all_kernel<<<dim3(256, 4), blk, 0, stream>>>(
        Wl_m0, Wr_m0, Wl_x0, Wr_x0, Wl_m1, Wr_m1, Wl_x1, Wr_x1,
        WT0m, WT0x, WT1m, WT1x);
    conv_rows_kernel<<<(N1v * Dv / 8 + 255) / 256, blk, 0, stream>>>(x, xtb, N1v * Dv);
    agg0_kernel<<<N1v / 4, blk, 0, stream>>>(x, row0, am, ax);

    // layer 0 (both GEMMs in one dispatch)
    gemm_mfma_kernel<1, 1><<<dim3((N1v + 127) / 128, 2, 2), blk, 0, stream>>>(
        am, ax, xtb, WT0m, WT0x, b_m0, b_x0, hm, hx, N1v, Dv, 0);

    // layer 1
    agg1_kernel<<<N2v / 8, blk, 0, stream>>>(hm, hx, row1, a1m, a1x);
    gemm_mfma_kernel<0, 0><<<dim3((N2v + 127) / 128, 2, 2), blk, 0, stream>>>(
        a1m, a1x, xtb, WT1m, WT1x, b_m1, b_x1, ocat, ocat, N2v, 2 * Dv, Dv);

    // post
    post_kernel<<<N2v, dim3(64), 0, stream>>>(ocat, W_post, b_post, out);
}

// Round 4
// 232.665 us; speedup vs baseline: 12.4991x; 1.0741x over previous
//
#include <hip/hip_runtime.h>
#include <hip/hip_bf16.h>
#include <math.h>

#define N0v 200000
#define N1v 50000
#define N2v 10000
#define Dv  256
#define Cv  40
#define DEGv 10

typedef __attribute__((ext_vector_type(8))) short          s16x8;
typedef __attribute__((ext_vector_type(8))) unsigned short u16x8;
typedef __attribute__((ext_vector_type(4))) float          f32x4;

static __device__ __forceinline__ unsigned short f2bf(float f) {
    __hip_bfloat16 h = __float2bfloat16(f);
    return *reinterpret_cast<unsigned short*>(&h);
}
static __device__ __forceinline__ float bf2f(unsigned short u) {
    __hip_bfloat16 h = *reinterpret_cast<__hip_bfloat16*>(&u);
    return __bfloat162float(h);
}

// async global -> LDS, 16B/lane, wave-uniform LDS base + lane*16 dest
static __device__ __forceinline__ void gload16(const void* g, void* l) {
    __builtin_amdgcn_global_load_lds(
        (const __attribute__((address_space(1))) unsigned int*)g,
        (__attribute__((address_space(3))) unsigned int*)l, 16, 0, 0);
}

// ---- prep: conv_rows (blocks [0,6250)) + conv_wt (blocks [6250,7274))
__global__ __launch_bounds__(256) void prep_kernel(
    const float* __restrict__ x, unsigned short* __restrict__ xtb,
    const float* __restrict__ Wl0, const float* __restrict__ Wr0,
    const float* __restrict__ Wl1, const float* __restrict__ Wr1,
    const float* __restrict__ Wl2, const float* __restrict__ Wr2,
    const float* __restrict__ Wl3, const float* __restrict__ Wr3,
    unsigned short* __restrict__ WT0, unsigned short* __restrict__ WT1,
    unsigned short* __restrict__ WT2, unsigned short* __restrict__ WT3)
{
    const int b = blockIdx.x;
    const int tid = threadIdx.x;
    if (b < 6250) {
        const int i = (b * 256 + tid) * 8;
        float4 v0 = *(const float4*)(x + i);
        float4 v1 = *(const float4*)(x + i + 4);
        unsigned short o[8] = { f2bf(v0.x), f2bf(v0.y), f2bf(v0.z), f2bf(v0.w),
                                f2bf(v1.x), f2bf(v1.y), f2bf(v1.z), f2bf(v1.w) };
        *(u16x8*)(xtb + i) = *(u16x8*)o;
    } else {
        const int idx = b - 6250;
        const int p = idx >> 8;
        const int n = idx & 255;
        const float* Wl = (p == 0) ? Wl0 : (p == 1) ? Wl1 : (p == 2) ? Wl2 : Wl3;
        const float* Wr = (p == 0) ? Wr0 : (p == 1) ? Wr1 : (p == 2) ? Wr2 : Wr3;
        unsigned short* WT = (p == 0) ? WT0 : (p == 1) ? WT1 : (p == 2) ? WT2 : WT3;
        WT[(size_t)n * 512 + tid]       = f2bf(Wl[(size_t)tid * Dv + n]);
        WT[(size_t)n * 512 + 256 + tid] = f2bf(Wr[(size_t)tid * Dv + n]);
    }
}

// ---- layer-0 aggregation: gather f32 x (float4/lane), write mean & max bf16
__global__ __launch_bounds__(256) void agg0_kernel(
    const float* __restrict__ x, const int* __restrict__ row,
    unsigned short* __restrict__ om, unsigned short* __restrict__ ox)
{
    const int t = blockIdx.x * 4 + (threadIdx.x >> 6);
    const int c = threadIdx.x & 63;
    const int eb = t * DEGv;
    float4 s = make_float4(0.f, 0.f, 0.f, 0.f);
    float4 mx = make_float4(-INFINITY, -INFINITY, -INFINITY, -INFINITY);
#pragma unroll
    for (int k = 0; k < DEGv; ++k) {
        const int r = row[eb + k];
        float4 v = ((const float4*)x)[(size_t)r * 64 + c];
        s.x += v.x; s.y += v.y; s.z += v.z; s.w += v.w;
        mx.x = fmaxf(mx.x, v.x); mx.y = fmaxf(mx.y, v.y);
        mx.z = fmaxf(mx.z, v.z); mx.w = fmaxf(mx.w, v.w);
    }
    const float inv = 1.0f / DEGv;
    unsigned short osum[4] = { f2bf(s.x * inv), f2bf(s.y * inv), f2bf(s.z * inv), f2bf(s.w * inv) };
    unsigned short omax[4] = { f2bf(mx.x), f2bf(mx.y), f2bf(mx.z), f2bf(mx.w) };
    *(uint2*)&om[(size_t)t * Dv + c * 4] = *(uint2*)osum;
    *(uint2*)&ox[(size_t)t * Dv + c * 4] = *(uint2*)omax;
}

// ---- layer-1 aggregation: gather bf16 (u16x8/lane), write mean & max bf16
__global__ __launch_bounds__(256) void agg1_kernel(
    const unsigned short* __restrict__ hm, const unsigned short* __restrict__ hx,
    const int* __restrict__ row,
    unsigned short* __restrict__ om, unsigned short* __restrict__ ox)
{
    const int t = blockIdx.x * 8 + (threadIdx.x >> 5);
    const int c = threadIdx.x & 31;
    const int eb = t * DEGv;
    float s[8] = {};
    float mx[8] = { -INFINITY, -INFINITY, -INFINITY, -INFINITY,
                    -INFINITY, -INFINITY, -INFINITY, -INFINITY };
#pragma unroll
    for (int k = 0; k < DEGv; ++k) {
        const int r = row[eb + k];
        u16x8 vm = ((const u16x8*)hm)[(size_t)r * 32 + c];
        u16x8 vx = ((const u16x8*)hx)[(size_t)r * 32 + c];
#pragma unroll
        for (int j = 0; j < 8; ++j) {
            s[j]  += bf2f(vm[j]);
            mx[j]  = fmaxf(mx[j], bf2f(vx[j]));
        }
    }
    const float inv = 1.0f / DEGv;
    unsigned short osum[8], omax[8];
#pragma unroll
    for (int j = 0; j < 8; ++j) { osum[j] = f2bf(s[j] * inv); omax[j] = f2bf(mx[j]); }
    *(u16x8*)&om[(size_t)t * Dv + c * 8] = *(u16x8*)osum;
    *(u16x8*)&ox[(size_t)t * Dv + c * 8] = *(u16x8*)omax;
}

// ---- bf16 MFMA GEMM: out_z = [relu]( [A1_z|A2] (Mx512) @ WT_z^T + bias_z )
// 128x128 tile, BK=64, 4 waves. global_load_lds staging with source-side XOR
// swizzle (rule 21): LDS slot s of row r holds global k-slot (s ^ (r&7)).
// ds_read uses the same XOR -> ~2-way conflicts (free).
template<int RELU, int OUTBF>
__global__ __launch_bounds__(256) void gemm_mfma_kernel(
    const unsigned short* __restrict__ A1a, const unsigned short* __restrict__ A1b,
    const unsigned short* __restrict__ A2,
    const unsigned short* __restrict__ WTa, const unsigned short* __restrict__ WTb,
    const float* __restrict__ biasa, const float* __restrict__ biasb,
    void* outa, void* outb, int M, int ldc, int col_step)
{
    __shared__ unsigned short Asb[128 * 64];   // 16 KB
    __shared__ unsigned short Bsb[128 * 64];   // 16 KB

    const int z = blockIdx.z;
    const unsigned short* A1 = z ? A1b : A1a;
    const unsigned short* WT = z ? WTb : WTa;
    const float* bias = z ? biasb : biasa;
    void* outp = z ? outb : outa;
    const int col_off = z * col_step;

    const int tid  = threadIdx.x;
    const int lane = tid & 63;
    const int w    = tid >> 6;
    const int wr   = w >> 1, wc = w & 1;
    const int m0   = blockIdx.x * 128, n0 = blockIdx.y * 128;

    // staging: wave w stages tile rows w*32 .. w*32+31; 4 gload16 per operand,
    // call c covers rows w*32+c*8 .. +7. lane -> local row (lane>>3),
    // swizzled source k-slot ((lane&7) ^ (lane>>3)).
    const int lrow = lane >> 3;
    const int scol = ((lane & 7) ^ lrow) * 8;   // elems

    const unsigned short* pA1[4];
    const unsigned short* pA2[4];
    const unsigned short* pB[4];
    unsigned short* lA[4];
    unsigned short* lB[4];
#pragma unroll
    for (int c = 0; c < 4; ++c) {
        const int r = w * 32 + c * 8 + lrow;
        int gm = m0 + r; if (gm >= M) gm = M - 1;
        pA1[c] = A1 + (size_t)gm * Dv + scol;
        pA2[c] = A2 + (size_t)gm * Dv + scol;
        pB[c]  = WT + (size_t)(n0 + r) * 512 + scol;
        lA[c] = &Asb[(w * 32 + c * 8) * 64];
        lB[c] = &Bsb[(w * 32 + c * 8) * 64];
    }

    const int fr = lane & 15;
    const int f7 = lane & 7;

    f32x4 acc[4][4] = {};

    for (int k0 = 0; k0 < 512; k0 += 64) {
        __syncthreads();                 // prior ds_reads done before overwrite
        if (k0 < 256) {
#pragma unroll
            for (int c = 0; c < 4; ++c) gload16(pA1[c] + k0, lA[c]);
        } else {
#pragma unroll
            for (int c = 0; c < 4; ++c) gload16(pA2[c] + (k0 - 256), lA[c]);
        }
#pragma unroll
        for (int c = 0; c < 4; ++c) gload16(pB[c] + k0, lB[c]);
        __syncthreads();                 // drains vmcnt before use

#pragma unroll
        for (int kk = 0; kk < 2; ++kk) {
            const int sl = kk * 4 + (lane >> 4);     // k-slot 0..7
            s16x8 af[4], bfr[4];
#pragma unroll
            for (int i = 0; i < 4; ++i) {
                const int ar = wr * 64 + i * 16 + fr;
                af[i]  = *(const s16x8*)&Asb[ar * 64 + ((sl ^ f7) << 3)];
                const int br = wc * 64 + i * 16 + fr;
                bfr[i] = *(const s16x8*)&Bsb[br * 64 + ((sl ^ f7) << 3)];
            }
#pragma unroll
            for (int i = 0; i < 4; ++i)
#pragma unroll
                for (int j = 0; j < 4; ++j)
                    acc[i][j] = __builtin_amdgcn_mfma_f32_16x16x32_bf16(af[i], bfr[j], acc[i][j], 0, 0, 0);
        }
    }

    // epilogue: C/D map col=lane&15, row=(lane>>4)*4+reg
#pragma unroll
    for (int i = 0; i < 4; ++i) {
#pragma unroll
        for (int reg = 0; reg < 4; ++reg) {
            const int gr = m0 + wr * 64 + i * 16 + (lane >> 4) * 4 + reg;
            if (gr < M) {
#pragma unroll
                for (int j = 0; j < 4; ++j) {
                    const int gc = n0 + wc * 64 + j * 16 + fr;
                    float v = acc[i][j][reg] + bias[gc];
                    if (RELU) v = fmaxf(v, 0.0f);
                    if (OUTBF)
                        ((unsigned short*)outp)[(size_t)gr * ldc + col_off + gc] = f2bf(v);
                    else
                        ((float*)outp)[(size_t)gr * ldc + col_off + gc] = v;
                }
            }
        }
    }
}

// ---- post: logits = ocat(bf16) @ W_post + b_post; log_softmax
__global__ __launch_bounds__(64) void post_kernel(
    const unsigned short* __restrict__ ocat, const float* __restrict__ Wp,
    const float* __restrict__ bp, float* __restrict__ out)
{
    __shared__ float srow[2 * Dv];
    __shared__ float slog[Cv];
    __shared__ float s_lse;

    const int t = blockIdx.x;
    const int tid = threadIdx.x;

    for (int i = tid; i < 2 * Dv; i += 64)
        srow[i] = bf2f(ocat[(size_t)t * (2 * Dv) + i]);
    __syncthreads();

    if (tid < Cv) {
        float acc = bp[tid];
#pragma unroll 8
        for (int k = 0; k < 2 * Dv; ++k)
            acc += srow[k] * Wp[(size_t)k * Cv + tid];
        slog[tid] = acc;
    }
    __syncthreads();

    if (tid == 0) {
        float m = slog[0];
        for (int c = 1; c < Cv; ++c) m = fmaxf(m, slog[c]);
        float s = 0.0f;
        for (int c = 0; c < Cv; ++c) s += expf(slog[c] - m);
        s_lse = m + logf(s);
    }
    __syncthreads();

    if (tid < Cv)
        out[(size_t)t * Cv + tid] = slog[tid] - s_lse;
}

extern "C" void kernel_launch(void* const* d_in, const int* in_sizes, int n_in,
                              void* d_out, int out_size, void* d_ws, size_t ws_size,
                              hipStream_t stream)
{
    const float* x      = (const float*)d_in[0];
    const int*   ei0    = (const int*)d_in[1];
    const int*   ei1    = (const int*)d_in[2];
    const float* Wl_m0  = (const float*)d_in[3];
    const float* Wr_m0  = (const float*)d_in[4];
    const float* b_m0   = (const float*)d_in[5];
    const float* Wl_x0  = (const float*)d_in[6];
    const float* Wr_x0  = (const float*)d_in[7];
    const float* b_x0   = (const float*)d_in[8];
    const float* Wl_m1  = (const float*)d_in[9];
    const float* Wr_m1  = (const float*)d_in[10];
    const float* b_m1   = (const float*)d_in[11];
    const float* Wl_x1  = (const float*)d_in[12];
    const float* Wr_x1  = (const float*)d_in[13];
    const float* b_x1   = (const float*)d_in[14];
    const float* W_post = (const float*)d_in[15];
    const float* b_post = (const float*)d_in[16];
    float* out = (float*)d_out;

    const int* row0 = ei0;   // edge_index0[0]
    const int* row1 = ei1;   // edge_index1[0]

    // workspace layout
    char* ws = (char*)d_ws;
    const size_t NB = (size_t)N1v * Dv * 2;                        // 25.6 MB
    unsigned short* xtb = (unsigned short*)(ws);
    unsigned short* am  = (unsigned short*)(ws + NB);
    unsigned short* ax  = (unsigned short*)(ws + 2 * NB);
    unsigned short* hm  = (unsigned short*)(ws + 3 * NB);
    unsigned short* hx  = (unsigned short*)(ws + 4 * NB);
    unsigned short* a1m = (unsigned short*)(ws + 5 * NB);
    unsigned short* a1x = a1m + (size_t)N2v * Dv;
    unsigned short* ocat = (unsigned short*)(ws + 5 * NB + (size_t)2 * N2v * Dv * 2);
    unsigned short* WT0m = ocat + (size_t)N2v * 2 * Dv;
    unsigned short* WT0x = WT0m + (size_t)256 * 512;
    unsigned short* WT1m = WT0x + (size_t)256 * 512;
    unsigned short* WT1x = WT1m + (size_t)256 * 512;

    const dim3 blk(256);

    // prep: xtb + 4 weight transposes in one dispatch
    prep_kernel<<<6250 + 1024, blk, 0, stream>>>(
        x, xtb,
        Wl_m0, Wr_m0, Wl_x0, Wr_x0, Wl_m1, Wr_m1, Wl_x1, Wr_x1,
        WT0m, WT0x, WT1m, WT1x);
    agg0_kernel<<<N1v / 4, blk, 0, stream>>>(x, row0, am, ax);

    // layer 0 (both GEMMs in one dispatch)
    gemm_mfma_kernel<1, 1><<<dim3((N1v + 127) / 128, 2, 2), blk, 0, stream>>>(
        am, ax, xtb, WT0m, WT0x, b_m0, b_x0, hm, hx, N1v, Dv, 0);

    // layer 1
    agg1_kernel<<<N2v / 8, blk, 0, stream>>>(hm, hx, row1, a1m, a1x);
    gemm_mfma_kernel<0, 1><<<dim3((N2v + 127) / 128, 2, 2), blk, 0, stream>>>(
        a1m, a1x, xtb, WT1m, WT1x, b_m1, b_x1, ocat, ocat, N2v, 2 * Dv, Dv);

    // post
    post_kernel<<<N2v, dim3(64), 0, stream>>>(ocat, W_post, b_post, out);
}

// Round 5
// 224.753 us; speedup vs baseline: 12.9391x; 1.0352x over previous
//
#include <hip/hip_runtime.h>
#include <hip/hip_bf16.h>
#include <math.h>

#define N0v 200000
#define N1v 50000
#define N2v 10000
#define Dv  256
#define Cv  40
#define DEGv 10

typedef __attribute__((ext_vector_type(8))) short          s16x8;
typedef __attribute__((ext_vector_type(8))) unsigned short u16x8;
typedef __attribute__((ext_vector_type(4))) float          f32x4;

static __device__ __forceinline__ unsigned short f2bf(float f) {
    __hip_bfloat16 h = __float2bfloat16(f);
    return *reinterpret_cast<unsigned short*>(&h);
}
static __device__ __forceinline__ float bf2f(unsigned short u) {
    __hip_bfloat16 h = *reinterpret_cast<__hip_bfloat16*>(&u);
    return __bfloat162float(h);
}

// async global -> LDS, 16B/lane, wave-uniform LDS base + lane*16 dest
static __device__ __forceinline__ void gload16(const void* g, void* l) {
    __builtin_amdgcn_global_load_lds(
        (const __attribute__((address_space(1))) unsigned int*)g,
        (__attribute__((address_space(3))) unsigned int*)l, 16, 0, 0);
}

// ---- weight prep: 4 pairs -> WT[n][k] bf16 (k<256 = Wl col, k>=256 = Wr col)
__global__ __launch_bounds__(256) void prep_kernel(
    const float* __restrict__ Wl0, const float* __restrict__ Wr0,
    const float* __restrict__ Wl1, const float* __restrict__ Wr1,
    const float* __restrict__ Wl2, const float* __restrict__ Wr2,
    const float* __restrict__ Wl3, const float* __restrict__ Wr3,
    unsigned short* __restrict__ WT0, unsigned short* __restrict__ WT1,
    unsigned short* __restrict__ WT2, unsigned short* __restrict__ WT3)
{
    const int idx = blockIdx.x;
    const int p = idx >> 8;
    const int n = idx & 255;
    const int k = threadIdx.x;
    const float* Wl = (p == 0) ? Wl0 : (p == 1) ? Wl1 : (p == 2) ? Wl2 : Wl3;
    const float* Wr = (p == 0) ? Wr0 : (p == 1) ? Wr1 : (p == 2) ? Wr2 : Wr3;
    unsigned short* WT = (p == 0) ? WT0 : (p == 1) ? WT1 : (p == 2) ? WT2 : WT3;
    WT[(size_t)n * 512 + k]       = f2bf(Wl[(size_t)k * Dv + n]);
    WT[(size_t)n * 512 + 256 + k] = f2bf(Wr[(size_t)k * Dv + n]);
}

// ---- layer-0 aggregation: gather f32 x (float4/lane), write mean & max bf16.
// Also converts x row t (this warp's own target row) to bf16 -> xtb.
__global__ __launch_bounds__(256) void agg0_kernel(
    const float* __restrict__ x, const int* __restrict__ row,
    unsigned short* __restrict__ om, unsigned short* __restrict__ ox,
    unsigned short* __restrict__ xtb)
{
    const int t = blockIdx.x * 4 + (threadIdx.x >> 6);
    const int c = threadIdx.x & 63;
    const int eb = t * DEGv;
    float4 s = make_float4(0.f, 0.f, 0.f, 0.f);
    float4 mx = make_float4(-INFINITY, -INFINITY, -INFINITY, -INFINITY);
#pragma unroll
    for (int k = 0; k < DEGv; ++k) {
        const int r = row[eb + k];
        float4 v = ((const float4*)x)[(size_t)r * 64 + c];
        s.x += v.x; s.y += v.y; s.z += v.z; s.w += v.w;
        mx.x = fmaxf(mx.x, v.x); mx.y = fmaxf(mx.y, v.y);
        mx.z = fmaxf(mx.z, v.z); mx.w = fmaxf(mx.w, v.w);
    }
    const float inv = 1.0f / DEGv;
    unsigned short osum[4] = { f2bf(s.x * inv), f2bf(s.y * inv), f2bf(s.z * inv), f2bf(s.w * inv) };
    unsigned short omax[4] = { f2bf(mx.x), f2bf(mx.y), f2bf(mx.z), f2bf(mx.w) };
    *(uint2*)&om[(size_t)t * Dv + c * 4] = *(uint2*)osum;
    *(uint2*)&ox[(size_t)t * Dv + c * 4] = *(uint2*)omax;

    // fused x[:50000] -> bf16 conversion (t < N1v always)
    float4 v = ((const float4*)x)[(size_t)t * 64 + c];
    unsigned short o[4] = { f2bf(v.x), f2bf(v.y), f2bf(v.z), f2bf(v.w) };
    *(uint2*)&xtb[(size_t)t * Dv + c * 4] = *(uint2*)o;
}

// ---- layer-1 aggregation: gather bf16 (u16x8/lane), write mean & max bf16
__global__ __launch_bounds__(256) void agg1_kernel(
    const unsigned short* __restrict__ hm, const unsigned short* __restrict__ hx,
    const int* __restrict__ row,
    unsigned short* __restrict__ om, unsigned short* __restrict__ ox)
{
    const int t = blockIdx.x * 8 + (threadIdx.x >> 5);
    const int c = threadIdx.x & 31;
    const int eb = t * DEGv;
    float s[8] = {};
    float mx[8] = { -INFINITY, -INFINITY, -INFINITY, -INFINITY,
                    -INFINITY, -INFINITY, -INFINITY, -INFINITY };
#pragma unroll
    for (int k = 0; k < DEGv; ++k) {
        const int r = row[eb + k];
        u16x8 vm = ((const u16x8*)hm)[(size_t)r * 32 + c];
        u16x8 vx = ((const u16x8*)hx)[(size_t)r * 32 + c];
#pragma unroll
        for (int j = 0; j < 8; ++j) {
            s[j]  += bf2f(vm[j]);
            mx[j]  = fmaxf(mx[j], bf2f(vx[j]));
        }
    }
    const float inv = 1.0f / DEGv;
    unsigned short osum[8], omax[8];
#pragma unroll
    for (int j = 0; j < 8; ++j) { osum[j] = f2bf(s[j] * inv); omax[j] = f2bf(mx[j]); }
    *(u16x8*)&om[(size_t)t * Dv + c * 8] = *(u16x8*)osum;
    *(u16x8*)&ox[(size_t)t * Dv + c * 8] = *(u16x8*)omax;
}

// ---- bf16 MFMA GEMM: out_z = [relu]( [A1_z|A2] (Mx512) @ WT_z^T + bias_z )
// 128x128 tile, BK=64, 4 waves. global_load_lds staging with source-side XOR
// swizzle (rule 21): LDS slot s of row r holds global k-slot (s ^ (r&7)).
template<int RELU, int OUTBF>
__global__ __launch_bounds__(256) void gemm_mfma_kernel(
    const unsigned short* __restrict__ A1a, const unsigned short* __restrict__ A1b,
    const unsigned short* __restrict__ A2,
    const unsigned short* __restrict__ WTa, const unsigned short* __restrict__ WTb,
    const float* __restrict__ biasa, const float* __restrict__ biasb,
    void* outa, void* outb, int M, int ldc, int col_step)
{
    __shared__ unsigned short Asb[128 * 64];   // 16 KB
    __shared__ unsigned short Bsb[128 * 64];   // 16 KB

    const int z = blockIdx.z;
    const unsigned short* A1 = z ? A1b : A1a;
    const unsigned short* WT = z ? WTb : WTa;
    const float* bias = z ? biasb : biasa;
    void* outp = z ? outb : outa;
    const int col_off = z * col_step;

    const int tid  = threadIdx.x;
    const int lane = tid & 63;
    const int w    = tid >> 6;
    const int wr   = w >> 1, wc = w & 1;
    const int m0   = blockIdx.x * 128, n0 = blockIdx.y * 128;

    const int lrow = lane >> 3;
    const int scol = ((lane & 7) ^ lrow) * 8;   // swizzled source k-slot

    const unsigned short* pA1[4];
    const unsigned short* pA2[4];
    const unsigned short* pB[4];
    unsigned short* lA[4];
    unsigned short* lB[4];
#pragma unroll
    for (int c = 0; c < 4; ++c) {
        const int r = w * 32 + c * 8 + lrow;
        int gm = m0 + r; if (gm >= M) gm = M - 1;
        pA1[c] = A1 + (size_t)gm * Dv + scol;
        pA2[c] = A2 + (size_t)gm * Dv + scol;
        pB[c]  = WT + (size_t)(n0 + r) * 512 + scol;
        lA[c] = &Asb[(w * 32 + c * 8) * 64];
        lB[c] = &Bsb[(w * 32 + c * 8) * 64];
    }

    const int fr = lane & 15;
    const int f7 = lane & 7;

    f32x4 acc[4][4] = {};

    for (int k0 = 0; k0 < 512; k0 += 64) {
        __syncthreads();
        if (k0 < 256) {
#pragma unroll
            for (int c = 0; c < 4; ++c) gload16(pA1[c] + k0, lA[c]);
        } else {
#pragma unroll
            for (int c = 0; c < 4; ++c) gload16(pA2[c] + (k0 - 256), lA[c]);
        }
#pragma unroll
        for (int c = 0; c < 4; ++c) gload16(pB[c] + k0, lB[c]);
        __syncthreads();

#pragma unroll
        for (int kk = 0; kk < 2; ++kk) {
            const int sl = kk * 4 + (lane >> 4);
            s16x8 af[4], bfr[4];
#pragma unroll
            for (int i = 0; i < 4; ++i) {
                const int ar = wr * 64 + i * 16 + fr;
                af[i]  = *(const s16x8*)&Asb[ar * 64 + ((sl ^ f7) << 3)];
                const int br = wc * 64 + i * 16 + fr;
                bfr[i] = *(const s16x8*)&Bsb[br * 64 + ((sl ^ f7) << 3)];
            }
#pragma unroll
            for (int i = 0; i < 4; ++i)
#pragma unroll
                for (int j = 0; j < 4; ++j)
                    acc[i][j] = __builtin_amdgcn_mfma_f32_16x16x32_bf16(af[i], bfr[j], acc[i][j], 0, 0, 0);
        }
    }

#pragma unroll
    for (int i = 0; i < 4; ++i) {
#pragma unroll
        for (int reg = 0; reg < 4; ++reg) {
            const int gr = m0 + wr * 64 + i * 16 + (lane >> 4) * 4 + reg;
            if (gr < M) {
#pragma unroll
                for (int j = 0; j < 4; ++j) {
                    const int gc = n0 + wc * 64 + j * 16 + fr;
                    float v = acc[i][j][reg] + bias[gc];
                    if (RELU) v = fmaxf(v, 0.0f);
                    if (OUTBF)
                        ((unsigned short*)outp)[(size_t)gr * ldc + col_off + gc] = f2bf(v);
                    else
                        ((float*)outp)[(size_t)gr * ldc + col_off + gc] = v;
                }
            }
        }
    }
}

// ---- post: logits = ocat(bf16, 10000x512) @ W_post(512x40) + b_post; log_softmax.
// 32 rows/block, 8-way K-split, W_post staged once per block in LDS (f32).
__global__ __launch_bounds__(256) void post_kernel(
    const unsigned short* __restrict__ ocat, const float* __restrict__ Wp,
    const float* __restrict__ bp, float* __restrict__ out, int nrows)
{
    __shared__ float sW[512 * 40];        // 80 KB
    __shared__ float sP[7][32][40];       // 35 KB partials (q=1..7)
    __shared__ float sb[Cv];

    const int tid = threadIdx.x;

    // stage W_post (5120 float4, 20/thread, coalesced)
    for (int i = tid; i < 5120; i += 256)
        ((float4*)sW)[i] = ((const float4*)Wp)[i];
    if (tid < Cv) sb[tid] = bp[tid];
    __syncthreads();

    const int q = tid >> 5;               // k-split 0..7 (64 k each)
    const int r = tid & 31;               // local row
    const int t = blockIdx.x * 32 + r;
    const bool valid = (t < nrows);

    float acc[Cv] = {};
    if (valid) {
        const unsigned short* prow = ocat + (size_t)t * 512 + q * 64;
        for (int kk = 0; kk < 64; kk += 8) {
            u16x8 v = *(const u16x8*)(prow + kk);
            const float* wbase = &sW[(q * 64 + kk) * Cv];
#pragma unroll
            for (int e = 0; e < 8; ++e) {
                const float xv = bf2f(v[e]);
                const float* wr_ = wbase + e * Cv;
#pragma unroll
                for (int c4 = 0; c4 < Cv; c4 += 4) {
                    f32x4 wv = *(const f32x4*)(wr_ + c4);
                    acc[c4 + 0] += xv * wv[0];
                    acc[c4 + 1] += xv * wv[1];
                    acc[c4 + 2] += xv * wv[2];
                    acc[c4 + 3] += xv * wv[3];
                }
            }
        }
    }

    if (q > 0) {
#pragma unroll
        for (int c4 = 0; c4 < Cv; c4 += 4)
            *(f32x4*)&sP[q - 1][r][c4] = *(f32x4*)&acc[c4];
    }
    __syncthreads();

    if (q == 0 && valid) {
#pragma unroll
        for (int p = 0; p < 7; ++p)
#pragma unroll
            for (int c4 = 0; c4 < Cv; c4 += 4) {
                f32x4 pv = *(const f32x4*)&sP[p][r][c4];
                acc[c4 + 0] += pv[0];
                acc[c4 + 1] += pv[1];
                acc[c4 + 2] += pv[2];
                acc[c4 + 3] += pv[3];
            }
        float m = -INFINITY;
#pragma unroll
        for (int c = 0; c < Cv; ++c) { acc[c] += sb[c]; m = fmaxf(m, acc[c]); }
        float s = 0.0f;
#pragma unroll
        for (int c = 0; c < Cv; ++c) s += expf(acc[c] - m);
        const float lse = m + logf(s);
        float* dst = out + (size_t)t * Cv;
#pragma unroll
        for (int c4 = 0; c4 < Cv; c4 += 4) {
            float o[4] = { acc[c4] - lse, acc[c4 + 1] - lse, acc[c4 + 2] - lse, acc[c4 + 3] - lse };
            *(float4*)(dst + c4) = *(float4*)o;
        }
    }
}

extern "C" void kernel_launch(void* const* d_in, const int* in_sizes, int n_in,
                              void* d_out, int out_size, void* d_ws, size_t ws_size,
                              hipStream_t stream)
{
    const float* x      = (const float*)d_in[0];
    const int*   ei0    = (const int*)d_in[1];
    const int*   ei1    = (const int*)d_in[2];
    const float* Wl_m0  = (const float*)d_in[3];
    const float* Wr_m0  = (const float*)d_in[4];
    const float* b_m0   = (const float*)d_in[5];
    const float* Wl_x0  = (const float*)d_in[6];
    const float* Wr_x0  = (const float*)d_in[7];
    const float* b_x0   = (const float*)d_in[8];
    const float* Wl_m1  = (const float*)d_in[9];
    const float* Wr_m1  = (const float*)d_in[10];
    const float* b_m1   = (const float*)d_in[11];
    const float* Wl_x1  = (const float*)d_in[12];
    const float* Wr_x1  = (const float*)d_in[13];
    const float* b_x1   = (const float*)d_in[14];
    const float* W_post = (const float*)d_in[15];
    const float* b_post = (const float*)d_in[16];
    float* out = (float*)d_out;

    const int* row0 = ei0;   // edge_index0[0]
    const int* row1 = ei1;   // edge_index1[0]

    // workspace layout
    char* ws = (char*)d_ws;
    const size_t NB = (size_t)N1v * Dv * 2;                        // 25.6 MB
    unsigned short* xtb = (unsigned short*)(ws);
    unsigned short* am  = (unsigned short*)(ws + NB);
    unsigned short* ax  = (unsigned short*)(ws + 2 * NB);
    unsigned short* hm  = (unsigned short*)(ws + 3 * NB);
    unsigned short* hx  = (unsigned short*)(ws + 4 * NB);
    unsigned short* a1m = (unsigned short*)(ws + 5 * NB);
    unsigned short* a1x = a1m + (size_t)N2v * Dv;
    unsigned short* ocat = (unsigned short*)(ws + 5 * NB + (size_t)2 * N2v * Dv * 2);
    unsigned short* WT0m = ocat + (size_t)N2v * 2 * Dv;
    unsigned short* WT0x = WT0m + (size_t)256 * 512;
    unsigned short* WT1m = WT0x + (size_t)256 * 512;
    unsigned short* WT1x = WT1m + (size_t)256 * 512;

    const dim3 blk(256);

    // weight prep (tiny) then fused agg0 + x->bf16 conversion
    prep_kernel<<<1024, blk, 0, stream>>>(
        Wl_m0, Wr_m0, Wl_x0, Wr_x0, Wl_m1, Wr_m1, Wl_x1, Wr_x1,
        WT0m, WT0x, WT1m, WT1x);
    agg0_kernel<<<N1v / 4, blk, 0, stream>>>(x, row0, am, ax, xtb);

    // layer 0 (both GEMMs in one dispatch)
    gemm_mfma_kernel<1, 1><<<dim3((N1v + 127) / 128, 2, 2), blk, 0, stream>>>(
        am, ax, xtb, WT0m, WT0x, b_m0, b_x0, hm, hx, N1v, Dv, 0);

    // layer 1
    agg1_kernel<<<N2v / 8, blk, 0, stream>>>(hm, hx, row1, a1m, a1x);
    gemm_mfma_kernel<0, 1><<<dim3((N2v + 127) / 128, 2, 2), blk, 0, stream>>>(
        a1m, a1x, xtb, WT1m, WT1x, b_m1, b_x1, ocat, ocat, N2v, 2 * Dv, Dv);

    // post
    post_kernel<<<(N2v + 31) / 32, blk, 0, stream>>>(ocat, W_post, b_post, out, N2v);
}

// Round 6
// 217.657 us; speedup vs baseline: 13.3610x; 1.0326x over previous
//
#include <hip/hip_runtime.h>
#include <hip/hip_bf16.h>
#include <math.h>

#define N0v 200000
#define N1v 50000
#define N2v 10000
#define Dv  256
#define Cv  40
#define DEGv 10

typedef __attribute__((ext_vector_type(8))) short          s16x8;
typedef __attribute__((ext_vector_type(8))) unsigned short u16x8;
typedef __attribute__((ext_vector_type(4))) float          f32x4;

static __device__ __forceinline__ unsigned short f2bf(float f) {
    __hip_bfloat16 h = __float2bfloat16(f);
    return *reinterpret_cast<unsigned short*>(&h);
}
static __device__ __forceinline__ float bf2f(unsigned short u) {
    __hip_bfloat16 h = *reinterpret_cast<__hip_bfloat16*>(&u);
    return __bfloat162float(h);
}

// async global -> LDS, 16B/lane, wave-uniform LDS base + lane*16 dest
static __device__ __forceinline__ void gload16(const void* g, void* l) {
    __builtin_amdgcn_global_load_lds(
        (const __attribute__((address_space(1))) unsigned int*)g,
        (__attribute__((address_space(3))) unsigned int*)l, 16, 0, 0);
}

// ---- fused: agg0 (blocks [0,12500)) + weight prep (blocks [12500,13524))
// agg0: gather f32 x (float4/lane), write mean & max bf16; also convert this
// warp's own x row to bf16 -> xtb.
// prep: 4 weight pairs -> WT[n][k] bf16 (k<256 = Wl col, k>=256 = Wr col).
__global__ __launch_bounds__(256) void agg0_prep_kernel(
    const float* __restrict__ x, const int* __restrict__ row,
    unsigned short* __restrict__ om, unsigned short* __restrict__ ox,
    unsigned short* __restrict__ xtb,
    const float* __restrict__ Wl0, const float* __restrict__ Wr0,
    const float* __restrict__ Wl1, const float* __restrict__ Wr1,
    const float* __restrict__ Wl2, const float* __restrict__ Wr2,
    const float* __restrict__ Wl3, const float* __restrict__ Wr3,
    unsigned short* __restrict__ WT0, unsigned short* __restrict__ WT1,
    unsigned short* __restrict__ WT2, unsigned short* __restrict__ WT3)
{
    const int b = blockIdx.x;
    if (b < 12500) {
        const int t = b * 4 + (threadIdx.x >> 6);
        const int c = threadIdx.x & 63;
        const int eb = t * DEGv;
        float4 s = make_float4(0.f, 0.f, 0.f, 0.f);
        float4 mx = make_float4(-INFINITY, -INFINITY, -INFINITY, -INFINITY);
#pragma unroll
        for (int k = 0; k < DEGv; ++k) {
            const int r = row[eb + k];
            float4 v = ((const float4*)x)[(size_t)r * 64 + c];
            s.x += v.x; s.y += v.y; s.z += v.z; s.w += v.w;
            mx.x = fmaxf(mx.x, v.x); mx.y = fmaxf(mx.y, v.y);
            mx.z = fmaxf(mx.z, v.z); mx.w = fmaxf(mx.w, v.w);
        }
        const float inv = 1.0f / DEGv;
        unsigned short osum[4] = { f2bf(s.x * inv), f2bf(s.y * inv), f2bf(s.z * inv), f2bf(s.w * inv) };
        unsigned short omax[4] = { f2bf(mx.x), f2bf(mx.y), f2bf(mx.z), f2bf(mx.w) };
        *(uint2*)&om[(size_t)t * Dv + c * 4] = *(uint2*)osum;
        *(uint2*)&ox[(size_t)t * Dv + c * 4] = *(uint2*)omax;

        float4 v = ((const float4*)x)[(size_t)t * 64 + c];
        unsigned short o[4] = { f2bf(v.x), f2bf(v.y), f2bf(v.z), f2bf(v.w) };
        *(uint2*)&xtb[(size_t)t * Dv + c * 4] = *(uint2*)o;
    } else {
        const int idx = b - 12500;
        const int p = idx >> 8;
        const int n = idx & 255;
        const int k = threadIdx.x;
        const float* Wl = (p == 0) ? Wl0 : (p == 1) ? Wl1 : (p == 2) ? Wl2 : Wl3;
        const float* Wr = (p == 0) ? Wr0 : (p == 1) ? Wr1 : (p == 2) ? Wr2 : Wr3;
        unsigned short* WT = (p == 0) ? WT0 : (p == 1) ? WT1 : (p == 2) ? WT2 : WT3;
        WT[(size_t)n * 512 + k]       = f2bf(Wl[(size_t)k * Dv + n]);
        WT[(size_t)n * 512 + 256 + k] = f2bf(Wr[(size_t)k * Dv + n]);
    }
}

// ---- layer-1 aggregation: gather bf16 (u16x8/lane), write mean & max bf16
__global__ __launch_bounds__(256) void agg1_kernel(
    const unsigned short* __restrict__ hm, const unsigned short* __restrict__ hx,
    const int* __restrict__ row,
    unsigned short* __restrict__ om, unsigned short* __restrict__ ox)
{
    const int t = blockIdx.x * 8 + (threadIdx.x >> 5);
    const int c = threadIdx.x & 31;
    const int eb = t * DEGv;
    float s[8] = {};
    float mx[8] = { -INFINITY, -INFINITY, -INFINITY, -INFINITY,
                    -INFINITY, -INFINITY, -INFINITY, -INFINITY };
#pragma unroll
    for (int k = 0; k < DEGv; ++k) {
        const int r = row[eb + k];
        u16x8 vm = ((const u16x8*)hm)[(size_t)r * 32 + c];
        u16x8 vx = ((const u16x8*)hx)[(size_t)r * 32 + c];
#pragma unroll
        for (int j = 0; j < 8; ++j) {
            s[j]  += bf2f(vm[j]);
            mx[j]  = fmaxf(mx[j], bf2f(vx[j]));
        }
    }
    const float inv = 1.0f / DEGv;
    unsigned short osum[8], omax[8];
#pragma unroll
    for (int j = 0; j < 8; ++j) { osum[j] = f2bf(s[j] * inv); omax[j] = f2bf(mx[j]); }
    *(u16x8*)&om[(size_t)t * Dv + c * 8] = *(u16x8*)osum;
    *(u16x8*)&ox[(size_t)t * Dv + c * 8] = *(u16x8*)omax;
}

// ---- bf16 MFMA GEMM: out_z = [relu]( [A1_z|A2] (Mx512) @ WT_z^T + bias_z )
// BM=128, BN=256 (full N, single n-tile), BK=64, 4 waves (2M x 2N),
// wave-tile 64x128 (4 M-frags x 8 N-frags). global_load_lds staging with
// source-side XOR swizzle (rule 21): LDS slot s of row r holds global
// k-slot (s ^ (r&7)); ds_read applies the same XOR.
template<int RELU, int OUTBF>
__global__ __launch_bounds__(256) void gemm_mfma_kernel(
    const unsigned short* __restrict__ A1a, const unsigned short* __restrict__ A1b,
    const unsigned short* __restrict__ A2,
    const unsigned short* __restrict__ WTa, const unsigned short* __restrict__ WTb,
    const float* __restrict__ biasa, const float* __restrict__ biasb,
    void* outa, void* outb, int M, int ldc, int col_step)
{
    __shared__ unsigned short Asb[128 * 64];   // 16 KB
    __shared__ unsigned short Bsb[256 * 64];   // 32 KB

    const int z = blockIdx.z;
    const unsigned short* A1 = z ? A1b : A1a;
    const unsigned short* WT = z ? WTb : WTa;
    const float* bias = z ? biasb : biasa;
    void* outp = z ? outb : outa;
    const int col_off = z * col_step;

    const int tid  = threadIdx.x;
    const int lane = tid & 63;
    const int w    = tid >> 6;
    const int wrow = w >> 1;        // M position (x64)
    const int wcol = w & 1;         // N position (x128)
    const int m0   = blockIdx.x * 128;

    const int lrow = lane >> 3;
    const int scol = ((lane & 7) ^ lrow) * 8;   // swizzled source k-slot (elems)

    // A staging: wave w covers tile rows w*32 .. +31 (4 gload16)
    const unsigned short* pA1[4];
    const unsigned short* pA2[4];
    unsigned short* lA[4];
#pragma unroll
    for (int c = 0; c < 4; ++c) {
        const int r = w * 32 + c * 8 + lrow;
        int gm = m0 + r; if (gm >= M) gm = M - 1;
        pA1[c] = A1 + (size_t)gm * Dv + scol;
        pA2[c] = A2 + (size_t)gm * Dv + scol;
        lA[c] = &Asb[(w * 32 + c * 8) * 64];
    }
    // B staging: wave w covers B rows w*64 .. +63 (8 gload16)
    const unsigned short* pB[8];
    unsigned short* lB[8];
#pragma unroll
    for (int c = 0; c < 8; ++c) {
        const int r = w * 64 + c * 8 + lrow;
        pB[c] = WT + (size_t)r * 512 + scol;
        lB[c] = &Bsb[(w * 64 + c * 8) * 64];
    }

    const int fr = lane & 15;
    const int f7 = lane & 7;

    f32x4 acc[4][8] = {};

    for (int k0 = 0; k0 < 512; k0 += 64) {
        __syncthreads();             // prior ds_reads done before overwrite
        if (k0 < 256) {
#pragma unroll
            for (int c = 0; c < 4; ++c) gload16(pA1[c] + k0, lA[c]);
        } else {
#pragma unroll
            for (int c = 0; c < 4; ++c) gload16(pA2[c] + (k0 - 256), lA[c]);
        }
#pragma unroll
        for (int c = 0; c < 8; ++c) gload16(pB[c] + k0, lB[c]);
        __syncthreads();             // drains vmcnt before use

#pragma unroll
        for (int kk = 0; kk < 2; ++kk) {
            const int sl = kk * 4 + (lane >> 4);
            const int so = ((sl ^ f7) << 3);
            s16x8 af[4];
#pragma unroll
            for (int i = 0; i < 4; ++i)
                af[i] = *(const s16x8*)&Asb[(wrow * 64 + i * 16 + fr) * 64 + so];
#pragma unroll
            for (int j = 0; j < 8; ++j) {
                s16x8 bv = *(const s16x8*)&Bsb[(wcol * 128 + j * 16 + fr) * 64 + so];
#pragma unroll
                for (int i = 0; i < 4; ++i)
                    acc[i][j] = __builtin_amdgcn_mfma_f32_16x16x32_bf16(af[i], bv, acc[i][j], 0, 0, 0);
            }
        }
    }

    // epilogue: C/D map col=lane&15, row=(lane>>4)*4+reg
#pragma unroll
    for (int i = 0; i < 4; ++i) {
#pragma unroll
        for (int reg = 0; reg < 4; ++reg) {
            const int gr = m0 + wrow * 64 + i * 16 + (lane >> 4) * 4 + reg;
            if (gr < M) {
#pragma unroll
                for (int j = 0; j < 8; ++j) {
                    const int gc = wcol * 128 + j * 16 + fr;
                    float v = acc[i][j][reg] + bias[gc];
                    if (RELU) v = fmaxf(v, 0.0f);
                    if (OUTBF)
                        ((unsigned short*)outp)[(size_t)gr * ldc + col_off + gc] = f2bf(v);
                    else
                        ((float*)outp)[(size_t)gr * ldc + col_off + gc] = v;
                }
            }
        }
    }
}

// ---- post: logits = ocat(bf16, 10000x512) @ W_post(512x40) + b_post; log_softmax.
// 32 rows/block, 8-way K-split, W_post staged once per block in LDS (f32).
__global__ __launch_bounds__(256) void post_kernel(
    const unsigned short* __restrict__ ocat, const float* __restrict__ Wp,
    const float* __restrict__ bp, float* __restrict__ out, int nrows)
{
    __shared__ float sW[512 * 40];        // 80 KB
    __shared__ float sP[7][32][40];       // 35 KB partials (q=1..7)
    __shared__ float sb[Cv];

    const int tid = threadIdx.x;

    for (int i = tid; i < 5120; i += 256)
        ((float4*)sW)[i] = ((const float4*)Wp)[i];
    if (tid < Cv) sb[tid] = bp[tid];
    __syncthreads();

    const int q = tid >> 5;               // k-split 0..7 (64 k each)
    const int r = tid & 31;               // local row
    const int t = blockIdx.x * 32 + r;
    const bool valid = (t < nrows);

    float acc[Cv] = {};
    if (valid) {
        const unsigned short* prow = ocat + (size_t)t * 512 + q * 64;
        for (int kk = 0; kk < 64; kk += 8) {
            u16x8 v = *(const u16x8*)(prow + kk);
            const float* wbase = &sW[(q * 64 + kk) * Cv];
#pragma unroll
            for (int e = 0; e < 8; ++e) {
                const float xv = bf2f(v[e]);
                const float* wr_ = wbase + e * Cv;
#pragma unroll
                for (int c4 = 0; c4 < Cv; c4 += 4) {
                    f32x4 wv = *(const f32x4*)(wr_ + c4);
                    acc[c4 + 0] += xv * wv[0];
                    acc[c4 + 1] += xv * wv[1];
                    acc[c4 + 2] += xv * wv[2];
                    acc[c4 + 3] += xv * wv[3];
                }
            }
        }
    }

    if (q > 0) {
#pragma unroll
        for (int c4 = 0; c4 < Cv; c4 += 4)
            *(f32x4*)&sP[q - 1][r][c4] = *(f32x4*)&acc[c4];
    }
    __syncthreads();

    if (q == 0 && valid) {
#pragma unroll
        for (int p = 0; p < 7; ++p)
#pragma unroll
            for (int c4 = 0; c4 < Cv; c4 += 4) {
                f32x4 pv = *(const f32x4*)&sP[p][r][c4];
                acc[c4 + 0] += pv[0];
                acc[c4 + 1] += pv[1];
                acc[c4 + 2] += pv[2];
                acc[c4 + 3] += pv[3];
            }
        float m = -INFINITY;
#pragma unroll
        for (int c = 0; c < Cv; ++c) { acc[c] += sb[c]; m = fmaxf(m, acc[c]); }
        float s = 0.0f;
#pragma unroll
        for (int c = 0; c < Cv; ++c) s += expf(acc[c] - m);
        const float lse = m + logf(s);
        float* dst = out + (size_t)t * Cv;
#pragma unroll
        for (int c4 = 0; c4 < Cv; c4 += 4) {
            float o[4] = { acc[c4] - lse, acc[c4 + 1] - lse, acc[c4 + 2] - lse, acc[c4 + 3] - lse };
            *(float4*)(dst + c4) = *(float4*)o;
        }
    }
}

extern "C" void kernel_launch(void* const* d_in, const int* in_sizes, int n_in,
                              void* d_out, int out_size, void* d_ws, size_t ws_size,
                              hipStream_t stream)
{
    const float* x      = (const float*)d_in[0];
    const int*   ei0    = (const int*)d_in[1];
    const int*   ei1    = (const int*)d_in[2];
    const float* Wl_m0  = (const float*)d_in[3];
    const float* Wr_m0  = (const float*)d_in[4];
    const float* b_m0   = (const float*)d_in[5];
    const float* Wl_x0  = (const float*)d_in[6];
    const float* Wr_x0  = (const float*)d_in[7];
    const float* b_x0   = (const float*)d_in[8];
    const float* Wl_m1  = (const float*)d_in[9];
    const float* Wr_m1  = (const float*)d_in[10];
    const float* b_m1   = (const float*)d_in[11];
    const float* Wl_x1  = (const float*)d_in[12];
    const float* Wr_x1  = (const float*)d_in[13];
    const float* b_x1   = (const float*)d_in[14];
    const float* W_post = (const float*)d_in[15];
    const float* b_post = (const float*)d_in[16];
    float* out = (float*)d_out;

    const int* row0 = ei0;   // edge_index0[0]
    const int* row1 = ei1;   // edge_index1[0]

    // workspace layout
    char* ws = (char*)d_ws;
    const size_t NB = (size_t)N1v * Dv * 2;                        // 25.6 MB
    unsigned short* xtb = (unsigned short*)(ws);
    unsigned short* am  = (unsigned short*)(ws + NB);
    unsigned short* ax  = (unsigned short*)(ws + 2 * NB);
    unsigned short* hm  = (unsigned short*)(ws + 3 * NB);
    unsigned short* hx  = (unsigned short*)(ws + 4 * NB);
    unsigned short* a1m = (unsigned short*)(ws + 5 * NB);
    unsigned short* a1x = a1m + (size_t)N2v * Dv;
    unsigned short* ocat = (unsigned short*)(ws + 5 * NB + (size_t)2 * N2v * Dv * 2);
    unsigned short* WT0m = ocat + (size_t)N2v * 2 * Dv;
    unsigned short* WT0x = WT0m + (size_t)256 * 512;
    unsigned short* WT1m = WT0x + (size_t)256 * 512;
    unsigned short* WT1x = WT1m + (size_t)256 * 512;

    const dim3 blk(256);

    // fused agg0 + x->bf16 + weight prep
    agg0_prep_kernel<<<12500 + 1024, blk, 0, stream>>>(
        x, row0, am, ax, xtb,
        Wl_m0, Wr_m0, Wl_x0, Wr_x0, Wl_m1, Wr_m1, Wl_x1, Wr_x1,
        WT0m, WT0x, WT1m, WT1x);

    // layer 0 (both GEMMs in one dispatch, full-N tile)
    gemm_mfma_kernel<1, 1><<<dim3((N1v + 127) / 128, 1, 2), blk, 0, stream>>>(
        am, ax, xtb, WT0m, WT0x, b_m0, b_x0, hm, hx, N1v, Dv, 0);

    // layer 1
    agg1_kernel<<<N2v / 8, blk, 0, stream>>>(hm, hx, row1, a1m, a1x);
    gemm_mfma_kernel<0, 1><<<dim3((N2v + 127) / 128, 1, 2), blk, 0, stream>>>(
        a1m, a1x, xtb, WT1m, WT1x, b_m1, b_x1, ocat, ocat, N2v, 2 * Dv, Dv);

    // post
    post_kernel<<<(N2v + 31) / 32, blk, 0, stream>>>(ocat, W_post, b_post, out, N2v);
}